// Round 10
// baseline (287.550 us; speedup 1.0000x reference)
//
#include <hip/hip_runtime.h>
#include <math.h>

#define TAU_F 32.0f

typedef __attribute__((ext_vector_type(8))) _Float16 half8;
typedef __attribute__((ext_vector_type(2))) __fp16 half2v;
typedef __attribute__((ext_vector_type(4))) float f32x4;

union HU { uint4 u; half8 v; };
union H2U { half2v h; unsigned int u; };

// async 16B/lane DMA: global -> LDS. lds dest must be WAVE-UNIFORM base
// (HW adds lane*16 itself); global src is per-lane.
__device__ __forceinline__ void gld_lds16(const void* g, void* l) {
    __builtin_amdgcn_global_load_lds(
        (const __attribute__((address_space(1))) void*)g,
        (__attribute__((address_space(3))) void*)l, 16, 0, 0);
}

// ============ Kernel 1: G partials, fp32 VALU, no atomics (unchanged) ============
// P[ks][192][2048], ks=4. Rows: 0..89 topic, 90..95 zero, 96..185 domain, 186..191 zero.
__global__ __launch_bounds__(256) void gproj2(
    const float* __restrict__ Wt, const float* __restrict__ Wd,
    const float* __restrict__ mem, const int* __restrict__ cat,
    float* __restrict__ P)
{
    __shared__ float Ml[96 * 36];
    __shared__ float Wl[32 * 68];

    const int bid = blockIdx.x;
    const int mat = bid >> 7;
    const int ks  = (bid >> 5) & 3;
    const int ct  = bid & 31;
    const int c0  = ct * 64;
    const int tid = threadIdx.x;
    const float* __restrict__ W = mat ? Wd : Wt;

    const int tr = tid >> 4;
    const int tc = tid & 15;

    float acc[6][4];
    #pragma unroll
    for (int j = 0; j < 6; ++j)
        #pragma unroll
        for (int q = 0; q < 4; ++q) acc[j][q] = 0.f;

    for (int ch = 0; ch < 6; ++ch) {
        __syncthreads();
        #pragma unroll
        for (int p = 0; p < 3; ++p) {
            const int idx = tid + 256 * p;
            const int r   = idx >> 3;
            const int kq  = idx & 7;
            float4 v = make_float4(0.f, 0.f, 0.f, 0.f);
            if (r < 90) {
                const int d = r / 10;
                const int mrow = cat[d] * 10 + (r - d * 10);
                v = *(const float4*)(mem + (size_t)mrow * 768 + ks * 192 + ch * 32 + kq * 4);
            }
            *(float4*)(Ml + r * 36 + kq * 4) = v;
        }
        #pragma unroll
        for (int p = 0; p < 2; ++p) {
            const int idx = tid + 256 * p;
            const int e   = idx >> 4;
            const int c4  = (idx & 15) * 4;
            *(float4*)(Wl + e * 68 + c4) =
                *(const float4*)(W + (size_t)(ks * 192 + ch * 32 + e) * 2048 + c0 + c4);
        }
        __syncthreads();

        #pragma unroll
        for (int e = 0; e < 32; e += 4) {
            float4 m4[6], w4[4];
            #pragma unroll
            for (int j = 0; j < 6; ++j) m4[j] = *(const float4*)(Ml + (tr * 6 + j) * 36 + e);
            #pragma unroll
            for (int q = 0; q < 4; ++q) w4[q] = *(const float4*)(Wl + (e + q) * 68 + tc * 4);
            #pragma unroll
            for (int j = 0; j < 6; ++j) {
                const float mv[4] = {m4[j].x, m4[j].y, m4[j].z, m4[j].w};
                #pragma unroll
                for (int q = 0; q < 4; ++q) {
                    acc[j][0] = fmaf(mv[q], w4[q].x, acc[j][0]);
                    acc[j][1] = fmaf(mv[q], w4[q].y, acc[j][1]);
                    acc[j][2] = fmaf(mv[q], w4[q].z, acc[j][2]);
                    acc[j][3] = fmaf(mv[q], w4[q].w, acc[j][3]);
                }
            }
        }
    }

    #pragma unroll
    for (int j = 0; j < 6; ++j) {
        float4 v = make_float4(acc[j][0], acc[j][1], acc[j][2], acc[j][3]);
        *(float4*)(P + (size_t)ks * 393216 + (size_t)(mat * 96 + tr * 6 + j) * 2048 + c0 + tc * 4) = v;
    }
}

// ============ Kernel 2: reduce partials -> f16 hi/lo, fragment-major (unchanged) ============
// col-frag cf = nq*3+j in 0..11 (0..5 topic, 6..11 domain);
// addr (halves) = ((kc*12 + cf)*2 + plane)*512 + lq*128 + lm*8
__global__ __launch_bounds__(256) void split_g3(
    const float* __restrict__ P, unsigned short* __restrict__ gB)
{
    const int u  = blockIdx.x * 256 + threadIdx.x;  // 0..49151
    const int n  = u >> 8;                          // 0..191
    const int k0 = (u & 255) * 8;                   // 0..2040

    float s[8] = {0.f, 0.f, 0.f, 0.f, 0.f, 0.f, 0.f, 0.f};
    #pragma unroll
    for (int ks = 0; ks < 4; ++ks) {
        const float4 a = *(const float4*)(P + (size_t)ks * 393216 + (size_t)n * 2048 + k0);
        const float4 b = *(const float4*)(P + (size_t)ks * 393216 + (size_t)n * 2048 + k0 + 4);
        s[0] += a.x; s[1] += a.y; s[2] += a.z; s[3] += a.w;
        s[4] += b.x; s[5] += b.y; s[6] += b.z; s[7] += b.w;
    }
    union { _Float16 h[8]; uint4 u4; } hi, lo;
    #pragma unroll
    for (int e = 0; e < 8; ++e) {
        const _Float16 h = (_Float16)s[e];   // RNE
        hi.h[e] = h;
        lo.h[e] = (_Float16)(s[e] - (float)h);
    }
    const int kc = k0 >> 5;
    const int lq = (k0 >> 3) & 3;
    const int nq = n / 48;
    const int rm = n - nq * 48;
    const int j  = rm >> 4;
    const int lm = rm & 15;
    const size_t fH = (size_t)((kc * 12 + nq * 3 + j) * 2 + 0) * 512 + lq * 128 + lm * 8;
    const size_t fL = (size_t)((kc * 12 + nq * 3 + j) * 2 + 1) * 512 + lq * 128 + lm * 8;
    *(uint4*)(gB + fH) = hi.u4;
    *(uint4*)(gB + fL) = lo.u4;
}

// ============ Kernel 3: DMA-staged-B split-f16 MFMA + fused softmax ============
// 512 blocks x 256 thr (4 waves), M=32 rows, 64 kc-steps of K=32, 2 blocks/CU.
// B: __builtin_amdgcn_global_load_lds gB->LDS double-buffer (18 x 1KB planes/step).
//    The DMA holds NO VGPRs -> the register allocator cannot sink/serialize it
//    (R4/R9 post-mortem: reg-prefetch was always sunk -> serial L2 latency/iter).
//    Drain is one vmcnt(0) at the barrier: BW-bound, overlapped with compute (m97).
// A: LDS dbuf staging (1 float4/thread/step), c1 global prefetch 2 steps ahead.
// Roles (w=0..3, 12 MFMA/step each; same accumulators and per-acc MFMA order as
// the R4-verified kernel, split per-kc in identical sequence => same score bits):
//   w<2 : topic frags {2w,2w+1}, 3 split-passes
//   w>=2: topic frag {2+w} (3 passes) + domain frags {6+3(w-2)..+2} (1 pass)
__global__ __launch_bounds__(256, 2) void fused_ep(
    const float* __restrict__ feat, const unsigned short* __restrict__ gB,
    float* __restrict__ out)
{
    // LDS (47,104 B): Bl [buf2][18 planes][1024 B] = 36,864 | aS [buf2][pl2][32][40h] = 10,240
    // sc [32][193] f32 = 24,704 overlays the front after the loop.
    __shared__ __align__(16) unsigned char smraw[47104];
    unsigned short* aS = (unsigned short*)(smraw + 36864);
    float* sc = (float*)smraw;
    __shared__ float ssqS[32];

    const int tid  = threadIdx.x;
    const int row0 = blockIdx.x * 32;

    const int w  = tid >> 6, l = tid & 63;
    const int lm = l & 15,  lq = l >> 4;
    const bool roleT = (w < 2);
    const int tf  = 2 + w;              // roleM topic frag (4 or 5)
    const int db  = 6 + 3 * (w - 2);    // roleM domain frags db..db+2
    const int sr = tid >> 3, sk = tid & 7;   // A staging: row 0..31, float4-slot 0..7

    f32x4 acc[2][4];
    #pragma unroll
    for (int i = 0; i < 2; ++i)
        #pragma unroll
        for (int j = 0; j < 4; ++j) acc[i][j] = (f32x4)0.f;
    float ssq = 0.f;

    const float* fbase = feat + (size_t)(row0 + sr) * 2048 + sk * 4;

    // ---- B plane DMA: plane p (0..17) of kc -> Bl[buf] + p*1024.
    // p<12: topic cf=p>>1, plane=p&1 ; p>=12: domain cf=p-6, hi plane.
    // Wave w stages planes {w, w+4, w+8, w+12, w+16<18}. Dest is wave-uniform. ----
    auto stageB = [&](int kc2, int buf) {
        #pragma unroll
        for (int s = 0; s < 5; ++s) {
            const int p = w + 4 * s;
            if (p < 18) {
                const int cf = (p < 12) ? (p >> 1) : (p - 6);
                const int pl = (p < 12) ? (p & 1) : 0;
                gld_lds16(gB + (size_t)(kc2 * 12 + cf) * 1024 + pl * 512 + l * 8,
                          smraw + buf * 18432 + p * 1024);
            }
        }
    };

    // convert+stage A (one float4/thread): fp32 -> f16 hi/lo planes, fused ssq
    auto cw = [&](int buf, float4 v) {
        ssq = fmaf(v.x, v.x, ssq); ssq = fmaf(v.y, v.y, ssq);
        ssq = fmaf(v.z, v.z, ssq); ssq = fmaf(v.w, v.w, ssq);
        H2U h0, h1, l0, l1;
        h0.h = __builtin_amdgcn_cvt_pkrtz(v.x, v.y);
        h1.h = __builtin_amdgcn_cvt_pkrtz(v.z, v.w);
        l0.h = __builtin_amdgcn_cvt_pkrtz(v.x - (float)h0.h[0], v.y - (float)h0.h[1]);
        l1.h = __builtin_amdgcn_cvt_pkrtz(v.z - (float)h1.h[0], v.w - (float)h1.h[1]);
        uint2 hi; hi.x = h0.u; hi.y = h1.u;
        uint2 lo; lo.x = l0.u; lo.y = l1.u;
        *(uint2*)(aS + (size_t)((buf * 2 + 0) * 32 + sr) * 40 + sk * 4) = hi;
        *(uint2*)(aS + (size_t)((buf * 2 + 1) * 32 + sr) * 40 + sk * 4) = lo;
    };

    // B fragment read from LDS plane p (halves): Bl half-base = buf*9216 + p*512 + l*8
    const unsigned short* BlH = (const unsigned short*)smraw;

    // ---- prologue ----
    float4 c1;
    {
        stageB(0, 0);
        float4 c0 = *(const float4*)(fbase);
        cw(0, c0);
        c1 = *(const float4*)(fbase + 32);
    }
    asm volatile("s_waitcnt vmcnt(0) lgkmcnt(0)" ::: "memory");
    __builtin_amdgcn_s_barrier();

    for (int kc = 0; kc < 64; ++kc) {
        const int cb = kc & 1;

        // 1. fire DMA for kc+1 into the other B buffer (no registers held)
        if (kc < 63) stageB(kc + 1, cb ^ 1);
        // 2. stage A(kc+1)
        if (kc < 63) cw(cb ^ 1, c1);

        // 3. A fragments (hi/lo) for both row-frags from aS[cb]
        half8 fh0, fh1, fl0, fl1;
        {
            HU a0, a1, b0, b1;
            a0.u = *(const uint4*)(aS + (size_t)((cb * 2 + 0) * 32 + 0 * 16 + lm) * 40 + lq * 8);
            a1.u = *(const uint4*)(aS + (size_t)((cb * 2 + 0) * 32 + 1 * 16 + lm) * 40 + lq * 8);
            b0.u = *(const uint4*)(aS + (size_t)((cb * 2 + 1) * 32 + 0 * 16 + lm) * 40 + lq * 8);
            b1.u = *(const uint4*)(aS + (size_t)((cb * 2 + 1) * 32 + 1 * 16 + lm) * 40 + lq * 8);
            fh0 = a0.v; fh1 = a1.v; fl0 = b0.v; fl1 = b1.v;
        }

        // 4. B fragments from Bl[cb] + MFMA (per-acc chain order == R4 kernel)
        const unsigned short* bp = BlH + (size_t)cb * 9216 + l * 8;
        if (roleT) {
            HU hA, hB, hC, hD;                       // planes 4w..4w+3
            hA.u = *(const uint4*)(bp + (size_t)(4 * w + 0) * 512);
            hB.u = *(const uint4*)(bp + (size_t)(4 * w + 1) * 512);
            hC.u = *(const uint4*)(bp + (size_t)(4 * w + 2) * 512);
            hD.u = *(const uint4*)(bp + (size_t)(4 * w + 3) * 512);
            acc[0][0] = __builtin_amdgcn_mfma_f32_16x16x32_f16(fh0, hA.v, acc[0][0], 0, 0, 0);
            acc[0][0] = __builtin_amdgcn_mfma_f32_16x16x32_f16(fh0, hB.v, acc[0][0], 0, 0, 0);
            acc[0][0] = __builtin_amdgcn_mfma_f32_16x16x32_f16(fl0, hA.v, acc[0][0], 0, 0, 0);
            acc[0][1] = __builtin_amdgcn_mfma_f32_16x16x32_f16(fh0, hC.v, acc[0][1], 0, 0, 0);
            acc[0][1] = __builtin_amdgcn_mfma_f32_16x16x32_f16(fh0, hD.v, acc[0][1], 0, 0, 0);
            acc[0][1] = __builtin_amdgcn_mfma_f32_16x16x32_f16(fl0, hC.v, acc[0][1], 0, 0, 0);
            acc[1][0] = __builtin_amdgcn_mfma_f32_16x16x32_f16(fh1, hA.v, acc[1][0], 0, 0, 0);
            acc[1][0] = __builtin_amdgcn_mfma_f32_16x16x32_f16(fh1, hB.v, acc[1][0], 0, 0, 0);
            acc[1][0] = __builtin_amdgcn_mfma_f32_16x16x32_f16(fl1, hA.v, acc[1][0], 0, 0, 0);
            acc[1][1] = __builtin_amdgcn_mfma_f32_16x16x32_f16(fh1, hC.v, acc[1][1], 0, 0, 0);
            acc[1][1] = __builtin_amdgcn_mfma_f32_16x16x32_f16(fh1, hD.v, acc[1][1], 0, 0, 0);
            acc[1][1] = __builtin_amdgcn_mfma_f32_16x16x32_f16(fl1, hC.v, acc[1][1], 0, 0, 0);
        } else {
            HU hA, hB, hC, hD, hE;                   // topic 2tf,2tf+1; domain 12+3(w-2)..
            hA.u = *(const uint4*)(bp + (size_t)(2 * tf + 0) * 512);
            hB.u = *(const uint4*)(bp + (size_t)(2 * tf + 1) * 512);
            hC.u = *(const uint4*)(bp + (size_t)(6 + db + 0) * 512);
            hD.u = *(const uint4*)(bp + (size_t)(6 + db + 1) * 512);
            hE.u = *(const uint4*)(bp + (size_t)(6 + db + 2) * 512);
            acc[0][0] = __builtin_amdgcn_mfma_f32_16x16x32_f16(fh0, hA.v, acc[0][0], 0, 0, 0);
            acc[0][0] = __builtin_amdgcn_mfma_f32_16x16x32_f16(fh0, hB.v, acc[0][0], 0, 0, 0);
            acc[0][0] = __builtin_amdgcn_mfma_f32_16x16x32_f16(fl0, hA.v, acc[0][0], 0, 0, 0);
            acc[0][1] = __builtin_amdgcn_mfma_f32_16x16x32_f16(fh0, hC.v, acc[0][1], 0, 0, 0);
            acc[0][2] = __builtin_amdgcn_mfma_f32_16x16x32_f16(fh0, hD.v, acc[0][2], 0, 0, 0);
            acc[0][3] = __builtin_amdgcn_mfma_f32_16x16x32_f16(fh0, hE.v, acc[0][3], 0, 0, 0);
            acc[1][0] = __builtin_amdgcn_mfma_f32_16x16x32_f16(fh1, hA.v, acc[1][0], 0, 0, 0);
            acc[1][0] = __builtin_amdgcn_mfma_f32_16x16x32_f16(fh1, hB.v, acc[1][0], 0, 0, 0);
            acc[1][0] = __builtin_amdgcn_mfma_f32_16x16x32_f16(fl1, hA.v, acc[1][0], 0, 0, 0);
            acc[1][1] = __builtin_amdgcn_mfma_f32_16x16x32_f16(fh1, hC.v, acc[1][1], 0, 0, 0);
            acc[1][2] = __builtin_amdgcn_mfma_f32_16x16x32_f16(fh1, hD.v, acc[1][2], 0, 0, 0);
            acc[1][3] = __builtin_amdgcn_mfma_f32_16x16x32_f16(fh1, hE.v, acc[1][3], 0, 0, 0);
        }

        // 5. A global prefetch for kc+2
        if (kc < 62) c1 = *(const float4*)(fbase + (kc + 2) * 32);

        // 6. m97-style drain: DMA completion is BW-bound here, not latency-bound
        asm volatile("s_waitcnt vmcnt(0) lgkmcnt(0)" ::: "memory");
        __builtin_amdgcn_s_barrier();
    }

    // ---- scores -> LDS (overlay; safe after final drain+barrier) ----
    if (roleT) {
        const int cf0 = 2 * w;
        #pragma unroll
        for (int i = 0; i < 2; ++i)
            #pragma unroll
            for (int r4 = 0; r4 < 4; ++r4) {
                sc[(i * 16 + lq * 4 + r4) * 193 + cf0 * 16 + lm]       = acc[i][0][r4];
                sc[(i * 16 + lq * 4 + r4) * 193 + (cf0 + 1) * 16 + lm] = acc[i][1][r4];
            }
    } else {
        #pragma unroll
        for (int i = 0; i < 2; ++i)
            #pragma unroll
            for (int r4 = 0; r4 < 4; ++r4) {
                sc[(i * 16 + lq * 4 + r4) * 193 + tf * 16 + lm]       = acc[i][0][r4];
                sc[(i * 16 + lq * 4 + r4) * 193 + db * 16 + lm]       = acc[i][1][r4];
                sc[(i * 16 + lq * 4 + r4) * 193 + (db + 1) * 16 + lm] = acc[i][2][r4];
                sc[(i * 16 + lq * 4 + r4) * 193 + (db + 2) * 16 + lm] = acc[i][3][r4];
            }
    }

    // ssq: 8 staging threads per row (sk 0..7) -> full-row |feat|^2
    ssq += __shfl_xor(ssq, 1, 64);
    ssq += __shfl_xor(ssq, 2, 64);
    ssq += __shfl_xor(ssq, 4, 64);
    if (sk == 0) ssqS[sr] = ssq;
    __syncthreads();

    // ---- softmax epilogue: 2 lanes per row (domains 0..4 / 5..8), wave 0 ----
    if (tid < 64) {
        const int rr = tid >> 1, hf = tid & 1;
        const int nd = hf ? 4 : 5;
        const int d0 = hf ? 5 : 0;
        const float inv = TAU_F / fmaxf(sqrtf(ssqS[rr]), 1e-12f);
        const float* scr = sc + (size_t)rr * 193;
        float lg[5];
        float dmax = -1e30f;
        #pragma unroll
        for (int dd = 0; dd < 5; ++dd) {
            if (dd < nd) {
                const int d = d0 + dd;
                const float* v = scr + d * 10;          // topic cols 0..89
                const float* u = scr + 96 + d * 10;     // domain cols 96..185
                float mx = v[0];
                #pragma unroll
                for (int m = 1; m < 10; ++m) mx = fmaxf(mx, v[m]);
                float ssum = 0.f, dot = 0.f;
                #pragma unroll
                for (int m = 0; m < 10; ++m) {
                    const float p = __expf((v[m] - mx) * inv);
                    ssum += p;
                    dot = fmaf(p, u[m], dot);
                }
                const float lgt = (dot / ssum) * inv;
                lg[dd] = lgt;
                dmax = fmaxf(dmax, lgt);
            } else {
                lg[dd] = -1e30f;                        // exp -> 0, doesn't affect sums
            }
        }
        dmax = fmaxf(dmax, __shfl_xor(dmax, 1, 64));
        float s2 = 0.f;
        #pragma unroll
        for (int dd = 0; dd < 5; ++dd) {
            const float p = __expf(lg[dd] - dmax);
            lg[dd] = p;
            s2 += p;
        }
        s2 += __shfl_xor(s2, 1, 64);
        const float r2 = 1.0f / s2;
        #pragma unroll
        for (int dd = 0; dd < 5; ++dd)
            if (dd < nd)
                out[(size_t)(row0 + rr) * 9 + d0 + dd] = lg[dd] * r2;
    }
}

extern "C" void kernel_launch(void* const* d_in, const int* in_sizes, int n_in,
                              void* d_out, int out_size, void* d_ws, size_t ws_size,
                              hipStream_t stream) {
    const float* feature = (const float*)d_in[0];
    const float* Wt      = (const float*)d_in[1];
    const float* Wd      = (const float*)d_in[2];
    const float* mem     = (const float*)d_in[3];
    const int*   cat     = (const int*)d_in[4];

    // ws layout: P (6.3 MB) | gB 1.57 MB @50331648
    float* P  = (float*)d_ws;
    unsigned short* gB = (unsigned short*)((char*)d_ws + 50331648);
    float* out = (float*)d_out;

    gproj2<<<256, 256, 0, stream>>>(Wt, Wd, mem, cat, P);
    split_g3<<<192, 256, 0, stream>>>(P, gB);
    fused_ep<<<512, 256, 0, stream>>>(feature, gB, out);
}